// Round 1
// baseline (142.130 us; speedup 1.0000x reference)
//
#include <hip/hip_runtime.h>
#include <hip/hip_bf16.h>
#include <math.h>

#define EPS 1e-8f
#define BB 32
#define SS 64
#define HH 200
#define LL 20
#define KST 232   // bf16 LDS row stride: 464B -> rows walk 8 banks, <=2-way on frag reads
#define SST 68    // att S-tile LDS row stride (floats)
#define MHS 200   // mean/max LDS row stride (floats)

typedef short bf16x8 __attribute__((ext_vector_type(8)));
typedef float f32x4 __attribute__((ext_vector_type(4)));

__device__ inline float bf2f(short u) {
    union { unsigned int i; float f; } v;
    v.i = ((unsigned int)(unsigned short)u) << 16;
    return v.f;
}

// ONE kernel, grid 1536 x 512 threads. No workspace at all.
//   blocks [0,256):    type A — att + attvec (mean/max kept in LDS) + matches m=0,1,2
//   blocks [256,1536): type C — pairwise MFMA, norms accumulated in-block (prep deleted)
//
// Type A LDS map (floats, 27648 total = 108 KB):
//   [0,3712)      AT   32xKST bf16   (phase 1-2)   \ overlay: PB 96xKST bf16 (phase 3)
//   [3712,11136)  BT   64xKST bf16   (phase 1-2)   /
//   [11136,13312) S_L  32xSST f32    (phase 1-2)   \ overlay: WB 32xKST bf16 (phase 3)
//   [13312,13440) nrmA(32) nrmB(64) dsum(32)       /
//   [14848,21248) meanL 32x200 f32   (phase 2-3)
//   [21248,27648) maxL  32x200 f32   (phase 2-3)
// Type C LDS map: AT 64xKST bf16 [0,7424) | BT [7424,14848) | cmL [14848,15104)
//                 nA [15104,15168) | nB [15168,15232)
__global__ __launch_bounds__(512) void fused_all_kernel(
        const float* __restrict__ conp, const float* __restrict__ conh,
        const float* __restrict__ w1, const float* __restrict__ w2,
        const float* __restrict__ w3, const float* __restrict__ w4,
        const float* __restrict__ w5, const float* __restrict__ w6,
        const float* __restrict__ w7, const float* __restrict__ w8,
        float* __restrict__ out) {
    __shared__ __align__(16) float smem[27648];   // 108 KB -> 1 block/CU
    int t = threadIdx.x;

    if (blockIdx.x < 256) {
        // ================================ type A
        __hip_bfloat16* AT = (__hip_bfloat16*)smem;
        __hip_bfloat16* BT = (__hip_bfloat16*)(smem + 3712);
        float* S_L  = smem + 11136;
        float* nrmA = smem + 13312;
        float* nrmB = nrmA + 32;
        float* dsum = nrmB + 64;
        __hip_bfloat16* PB = (__hip_bfloat16*)smem;            // phase 3: 96xKST
        __hip_bfloat16* WB = (__hip_bfloat16*)(smem + 11136);  // phase 3: 32xKST
        float* meanL = smem + 14848;
        float* maxL  = smem + 21248;

        int blk = blockIdx.x;
        int sh = blk & 1;
        int sdb = blk >> 1;
        int b = sdb & 31, sd = sdb >> 5;
        int dir = sd & 1, side = sd >> 1;
        const float* selfb = side ? conh : conp;
        const float* oppb  = side ? conp : conh;

        if (t < 32) nrmA[t] = 0.f;
        if (t < 64) nrmB[t] = 0.f;
        __syncthreads();

        // ---- phase 1: stage self rows (A) + opp rows (B) as bf16, accumulate norms
        for (int e = t; e < 32 * 28; e += 512) {
            int sl = e / 28, ck = e % 28, k = ck * 8;
            __align__(16) __hip_bfloat16 r8[8];
            if (k < HH) {
                const float* xp = selfb + (b * SS + sh * 32 + sl) * (2 * HH) + dir * HH + k;
                float xv[8];
                *(float4*)&xv[0] = *(const float4*)xp; *(float4*)&xv[4] = *(const float4*)(xp + 4);
                float ss = 0.f;
#pragma unroll
                for (int i = 0; i < 8; ++i) { r8[i] = __float2bfloat16(xv[i]); ss = fmaf(xv[i], xv[i], ss); }
                atomicAdd(&nrmA[sl], ss);
            } else {
#pragma unroll
                for (int i = 0; i < 8; ++i) r8[i] = __float2bfloat16(0.f);
            }
            *(bf16x8*)&AT[sl * KST + k] = *(bf16x8*)r8;
        }
        for (int e = t; e < 64 * 28; e += 512) {
            int rw = e / 28, ck = e % 28, k = ck * 8;
            __align__(16) __hip_bfloat16 r8[8];
            if (k < HH) {
                const float* xp = oppb + (b * SS + rw) * (2 * HH) + dir * HH + k;
                float xv[8];
                *(float4*)&xv[0] = *(const float4*)xp; *(float4*)&xv[4] = *(const float4*)(xp + 4);
                float ss = 0.f;
#pragma unroll
                for (int i = 0; i < 8; ++i) { r8[i] = __float2bfloat16(xv[i]); ss = fmaf(xv[i], xv[i], ss); }
                atomicAdd(&nrmB[rw], ss);
            } else {
#pragma unroll
                for (int i = 0; i < 8; ++i) r8[i] = __float2bfloat16(0.f);
            }
            *(bf16x8*)&BT[rw * KST + k] = *(bf16x8*)r8;
        }
        __syncthreads();

        int wv_ = __builtin_amdgcn_readfirstlane(t >> 6);
        int lane = t & 63;
        int q = lane >> 4, c = lane & 15;

        // ---- S = cos(A, B) via MFMA: 8 waves, one 16x16 tile each
        {
            int rt = wv_ & 1, ct = wv_ >> 1;
            f32x4 acc = (f32x4){0.f, 0.f, 0.f, 0.f};
            for (int ks = 0; ks < 7; ++ks) {
                int kb = ks * 32 + q * 8;
                bf16x8 af  = *(const bf16x8*)&AT[(rt * 16 + c) * KST + kb];
                bf16x8 bf_ = *(const bf16x8*)&BT[(ct * 16 + c) * KST + kb];
                acc = __builtin_amdgcn_mfma_f32_16x16x32_bf16(af, bf_, acc, 0, 0, 0);
            }
            int col = ct * 16 + c;
            float no = sqrtf(nrmB[col]);
#pragma unroll
            for (int r = 0; r < 4; ++r) {
                int row = rt * 16 + q * 4 + r;
                float ns = sqrtf(nrmA[row]);
                S_L[row * SST + col] = acc[r] / fmaxf(ns * no, EPS);
            }
        }
        __syncthreads();

        if (t < 32) {
            float sm = 0.f;
            for (int k = 0; k < 64; ++k) sm += S_L[t * SST + k];
            dsum[t] = fmaxf(sm, EPS);
        }
        __syncthreads();

        // ---- phase 2: attvec -> meanL / maxL (stay in LDS, f32)
        for (int e = t; e < 32 * 25; e += 512) {
            int s = e / 25, hc = e % 25, h0 = hc * 8;
            float dsv = dsum[s];
            float ms[8], mx[8];
#pragma unroll
            for (int i = 0; i < 8; ++i) { ms[i] = 0.f; mx[i] = -INFINITY; }
            for (int k = 0; k < 64; ++k) {
                float a = S_L[s * SST + k];
                bf16x8 ov = *(const bf16x8*)&BT[k * KST + h0];
#pragma unroll
                for (int i = 0; i < 8; ++i) {
                    float tt = a * bf2f(ov[i]);
                    ms[i] += tt;
                    mx[i] = fmaxf(mx[i], tt);
                }
            }
#pragma unroll
            for (int i = 0; i < 8; ++i) ms[i] /= dsv;
            *(float4*)&meanL[s * MHS + h0]     = *(float4*)&ms[0];
            *(float4*)&meanL[s * MHS + h0 + 4] = *(float4*)&ms[4];
            *(float4*)&maxL[s * MHS + h0]      = *(float4*)&mx[0];
            *(float4*)&maxL[s * MHS + h0 + 4]  = *(float4*)&mx[4];
        }
        __syncthreads();   // PB/WB overlays about to overwrite AT/BT/S_L/dsum

        // ---- phase 3: matches m=0 (full), m=1 (att_mean), m=2 (att_max)
        int fidx = dir ? 0 : (SS - 1);
        const float* fvr = oppb + (b * SS + fidx) * (2 * HH) + dir * HH;
        for (int m = 0; m < 3; ++m) {
            const float* wsrc = (m == 0) ? (dir ? w2 : w1)
                              : (m == 1) ? (dir ? w6 : w5)
                                         : (dir ? w8 : w7);
            // stage products [x^2 ; x*y ; y^2] (x^2 persists from m=0)
            for (int e = t; e < 32 * 28; e += 512) {
                int sl = e / 28, ck = e % 28, k = ck * 8;
                __align__(16) __hip_bfloat16 r0[8], r1[8], r2[8];
                if (k < HH) {
                    const float* xp = selfb + (b * SS + sh * 32 + sl) * (2 * HH) + dir * HH + k;
                    float xv[8], yv[8];
                    *(float4*)&xv[0] = *(const float4*)xp; *(float4*)&xv[4] = *(const float4*)(xp + 4);
                    if (m == 0) {
                        *(float4*)&yv[0] = *(const float4*)(fvr + k);
                        *(float4*)&yv[4] = *(const float4*)(fvr + k + 4);
                    } else {
                        const float* yL = (m == 1 ? meanL : maxL) + sl * MHS + k;
                        *(float4*)&yv[0] = *(const float4*)yL;
                        *(float4*)&yv[4] = *(const float4*)(yL + 4);
                    }
#pragma unroll
                    for (int i = 0; i < 8; ++i) {
                        if (m == 0) r0[i] = __float2bfloat16(xv[i] * xv[i]);
                        r1[i] = __float2bfloat16(xv[i] * yv[i]);
                        r2[i] = __float2bfloat16(yv[i] * yv[i]);
                    }
                } else {
#pragma unroll
                    for (int i = 0; i < 8; ++i) {
                        r0[i] = __float2bfloat16(0.f);
                        r1[i] = __float2bfloat16(0.f);
                        r2[i] = __float2bfloat16(0.f);
                    }
                }
                if (m == 0) *(bf16x8*)&PB[(0 * 32 + sl) * KST + k] = *(bf16x8*)r0;
                *(bf16x8*)&PB[(1 * 32 + sl) * KST + k] = *(bf16x8*)r1;
                *(bf16x8*)&PB[(2 * 32 + sl) * KST + k] = *(bf16x8*)r2;
            }
            // stage w^2
            for (int e = t; e < 32 * 28; e += 512) {
                int l_ = e / 28, ck = e % 28, k = ck * 8;
                __align__(16) __hip_bfloat16 wr[8];
                if (l_ < LL && k < HH) {
                    const float* wp = wsrc + l_ * HH + k;
                    float wv[8];
                    *(float4*)&wv[0] = *(const float4*)wp; *(float4*)&wv[4] = *(const float4*)(wp + 4);
#pragma unroll
                    for (int i = 0; i < 8; ++i) wr[i] = __float2bfloat16(wv[i] * wv[i]);
                } else {
#pragma unroll
                    for (int i = 0; i < 8; ++i) wr[i] = __float2bfloat16(0.f);
                }
                *(bf16x8*)&WB[l_ * KST + k] = *(bf16x8*)wr;
            }
            __syncthreads();

            if (wv_ < 4) {
                int slh = wv_ >> 1, ntile = wv_ & 1;
                f32x4 accA = (f32x4){0.f, 0.f, 0.f, 0.f};
                f32x4 accD = (f32x4){0.f, 0.f, 0.f, 0.f};
                f32x4 accB = (f32x4){0.f, 0.f, 0.f, 0.f};
                for (int ks = 0; ks < 7; ++ks) {
                    int kb = ks * 32 + q * 8;
                    bf16x8 bfw = *(const bf16x8*)&WB[(ntile * 16 + c) * KST + kb];
                    bf16x8 a0 = *(const bf16x8*)&PB[(0 * 32 + slh * 16 + c) * KST + kb];
                    bf16x8 a1 = *(const bf16x8*)&PB[(1 * 32 + slh * 16 + c) * KST + kb];
                    bf16x8 a2 = *(const bf16x8*)&PB[(2 * 32 + slh * 16 + c) * KST + kb];
                    accA = __builtin_amdgcn_mfma_f32_16x16x32_bf16(a0, bfw, accA, 0, 0, 0);
                    accD = __builtin_amdgcn_mfma_f32_16x16x32_bf16(a1, bfw, accD, 0, 0, 0);
                    accB = __builtin_amdgcn_mfma_f32_16x16x32_bf16(a2, bfw, accB, 0, 0, 0);
                }
                int l_ = ntile * 16 + c;
                if (l_ < LL) {
                    int chunk = (m == 0) ? 0 : (m == 1) ? 40 : 60;
#pragma unroll
                    for (int r = 0; r < 4; ++r) {
                        int s = sh * 32 + slh * 16 + q * 4 + r;
                        float cosv = accD[r] / fmaxf(sqrtf(accA[r] * accB[r]), EPS);
                        out[side * (BB * SS * 160) + (b * SS + s) * 160 + dir * 80 + chunk + l_] = cosv;
                    }
                }
            }
            if (m < 2) __syncthreads();
        }
    } else {
        // ================================ type C: pairwise MFMA, in-block norms
        __hip_bfloat16* AT = (__hip_bfloat16*)smem;            // 64*KST bf16
        __hip_bfloat16* BT = (__hip_bfloat16*)(smem + 7424);   // 64*KST bf16
        float* cmL = smem + 14848;                             // 256
        float* nA  = smem + 15104;                             // 64
        float* nB  = smem + 15168;                             // 64
        int blk = blockIdx.x - 256;
        int l = blk % LL; int db = blk / LL; int b = db & 31; int dir = db >> 5;

        const float* wrow = (dir ? w4 : w3) + l * HH;
        const float* Ag = conp + dir * HH;
        const float* Bg = conh + dir * HH;

        if (t < 64) { nA[t] = 0.f; nB[t] = 0.f; }
        __syncthreads();

        for (int e = t; e < 64 * 28; e += 512) {
            int m = e / 28, ck = e - m * 28;
            int k = ck * 8;
            __align__(16) __hip_bfloat16 at8[8];
            __align__(16) __hip_bfloat16 bt8[8];
            if (k < HH) {
                const float* ap = Ag + (b * SS + m) * (2 * HH) + k;
                const float* bp = Bg + (b * SS + m) * (2 * HH) + k;
                const float* wp = wrow + k;
                float av[8], bv[8], wvv[8];
                *(float4*)&av[0]  = *(const float4*)ap; *(float4*)&av[4]  = *(const float4*)(ap + 4);
                *(float4*)&bv[0]  = *(const float4*)bp; *(float4*)&bv[4]  = *(const float4*)(bp + 4);
                *(float4*)&wvv[0] = *(const float4*)wp; *(float4*)&wvv[4] = *(const float4*)(wp + 4);
                float ssa = 0.f, ssb = 0.f;
#pragma unroll
                for (int i = 0; i < 8; ++i) {
                    float aw = av[i] * wvv[i];
                    float bw = bv[i] * wvv[i];
                    at8[i] = __float2bfloat16(aw);
                    bt8[i] = __float2bfloat16(bw);
                    ssa = fmaf(aw, aw, ssa);
                    ssb = fmaf(bw, bw, ssb);
                }
                atomicAdd(&nA[m], ssa);
                atomicAdd(&nB[m], ssb);
            } else {
#pragma unroll
                for (int ii = 0; ii < 8; ++ii) { at8[ii] = __float2bfloat16(0.f); bt8[ii] = __float2bfloat16(0.f); }
            }
            *(bf16x8*)&AT[m * KST + k] = *(bf16x8*)at8;
            *(bf16x8*)&BT[m * KST + k] = *(bf16x8*)bt8;
        }
        __syncthreads();

        int wv_ = __builtin_amdgcn_readfirstlane(t >> 6);
        int lane = t & 63;
        int q = lane >> 4, c = lane & 15;

        if (wv_ < 4) {
            int m0 = wv_ * 16;
            f32x4 acc[4];
#pragma unroll
            for (int ct = 0; ct < 4; ++ct) acc[ct] = (f32x4){0.f, 0.f, 0.f, 0.f};
            for (int ks = 0; ks < 7; ++ks) {
                int kb = ks * 32 + q * 8;
                bf16x8 af = *(const bf16x8*)&AT[(m0 + c) * KST + kb];
#pragma unroll
                for (int ct = 0; ct < 4; ++ct) {
                    bf16x8 bf_ = *(const bf16x8*)&BT[(ct * 16 + c) * KST + kb];
                    acc[ct] = __builtin_amdgcn_mfma_f32_16x16x32_bf16(af, bf_, acc[ct], 0, 0, 0);
                }
            }

            float na[4], nb[4];
#pragma unroll
            for (int r = 0; r < 4; ++r) na[r] = sqrtf(nA[m0 + q * 4 + r]);
#pragma unroll
            for (int ct = 0; ct < 4; ++ct) nb[ct] = sqrtf(nB[ct * 16 + c]);

            float rowm[4] = {-INFINITY, -INFINITY, -INFINITY, -INFINITY};
            float colm[4] = {-INFINITY, -INFINITY, -INFINITY, -INFINITY};
#pragma unroll
            for (int ct = 0; ct < 4; ++ct) {
#pragma unroll
                for (int r = 0; r < 4; ++r) {
                    float cv = acc[ct][r] / fmaxf(na[r] * nb[ct], EPS);
                    rowm[r] = fmaxf(rowm[r], cv);
                    colm[ct] = fmaxf(colm[ct], cv);
                }
            }

#pragma unroll
            for (int r = 0; r < 4; ++r) {
                float v = rowm[r];
                v = fmaxf(v, __shfl_xor(v, 1, 64));
                v = fmaxf(v, __shfl_xor(v, 2, 64));
                v = fmaxf(v, __shfl_xor(v, 4, 64));
                v = fmaxf(v, __shfl_xor(v, 8, 64));
                rowm[r] = v;
            }
            if (c == 0) {
#pragma unroll
                for (int r = 0; r < 4; ++r) {
                    int i = m0 + q * 4 + r;
                    out[(b * SS + i) * 160 + dir * 80 + 20 + l] = rowm[r];
                }
            }

#pragma unroll
            for (int ct = 0; ct < 4; ++ct) {
                float v = colm[ct];
                v = fmaxf(v, __shfl_xor(v, 16, 64));
                v = fmaxf(v, __shfl_xor(v, 32, 64));
                colm[ct] = v;
            }
            if (q == 0) {
#pragma unroll
                for (int ct = 0; ct < 4; ++ct) cmL[wv_ * 64 + ct * 16 + c] = colm[ct];
            }
        }
        __syncthreads();
        if (t < 64) {
            float mm = fmaxf(fmaxf(cmL[t], cmL[64 + t]), fmaxf(cmL[128 + t], cmL[192 + t]));
            out[BB * SS * 160 + (b * SS + t) * 160 + dir * 80 + 20 + l] = mm;
        }
    }
}

extern "C" void kernel_launch(void* const* d_in, const int* in_sizes, int n_in,
                              void* d_out, int out_size, void* d_ws, size_t ws_size,
                              hipStream_t stream) {
    const float* conp = (const float*)d_in[0];
    const float* conh = (const float*)d_in[1];
    const float* w1 = (const float*)d_in[2];
    const float* w2 = (const float*)d_in[3];
    const float* w3 = (const float*)d_in[4];
    const float* w4 = (const float*)d_in[5];
    const float* w5 = (const float*)d_in[6];
    const float* w6 = (const float*)d_in[7];
    const float* w7 = (const float*)d_in[8];
    const float* w8 = (const float*)d_in[9];
    float* out = (float*)d_out;
    (void)d_ws; (void)ws_size;   // workspace no longer used

    fused_all_kernel<<<1536, 512, 0, stream>>>(conp, conh,
                                               w1, w2, w3, w4, w5, w6, w7, w8, out);
}

// Round 3
// 133.308 us; speedup vs baseline: 1.0662x; 1.0662x over previous
//
#include <hip/hip_runtime.h>
#include <hip/hip_bf16.h>
#include <math.h>

#define EPS 1e-8f
#define BB 32
#define SS 64
#define HH 200
#define LL 20
#define KST 232   // bf16 LDS row stride
#define SST 68    // S-tile LDS row stride (floats)
#define MHS 200   // mean/max LDS row stride (floats)

typedef short bf16x8 __attribute__((ext_vector_type(8)));
typedef float f32x4 __attribute__((ext_vector_type(4)));

__device__ inline float bf2f(short u) {
    union { unsigned int i; float f; } v;
    v.i = ((unsigned int)(unsigned short)u) << 16;
    return v.f;
}

// ONE kernel, grid 1792 x 512. No workspace.
//   blocks [0,512):    type A — 16 self-rows: att S + attvec (mean/max in LDS f32) + matches m=0,1,2
//                      (round-1 math verbatim, rows 32->16)
//   blocks [512,1792): type C — pairwise MFMA, VERBATIM round-1 (atomic norms, 4-wave MFMA)
//
// Type A LDS (floats, 19392 = 77.6 KB -> 2 blocks/CU):
//   [0,1856)       AT 16xKST bf16      \ overlay PB 48xKST bf16 [0,5568)
//   [1856,9280)    BT 64xKST bf16      /
//   [9280,10368)   S_L 16xSST f32      \ overlay WB 32xKST bf16 [9280,12992)
//   [10368,10464)  nrmA(16) nrmB(64) dsum(16) /
//   [12992,16192)  meanL 16x200 f32
//   [16192,19392)  maxL  16x200 f32
// Type C LDS: AT 64xKST [0,7424) | BT [7424,14848) | cmL [14848,15104)
//             nA [15104,15168) | nB [15168,15232)
__global__ __launch_bounds__(512) void fused_all_kernel(
        const float* __restrict__ conp, const float* __restrict__ conh,
        const float* __restrict__ w1, const float* __restrict__ w2,
        const float* __restrict__ w3, const float* __restrict__ w4,
        const float* __restrict__ w5, const float* __restrict__ w6,
        const float* __restrict__ w7, const float* __restrict__ w8,
        float* __restrict__ out) {
    __shared__ __align__(16) float smem[19392];
    int t = threadIdx.x;

    if (blockIdx.x < 512) {
        // ================================ type A (16 self-rows, round-1 structure)
        __hip_bfloat16* AT = (__hip_bfloat16*)smem;
        __hip_bfloat16* BT = (__hip_bfloat16*)(smem + 1856);
        float* S_L  = smem + 9280;
        float* nrmA = smem + 10368;
        float* nrmB = smem + 10384;
        float* dsum = smem + 10448;
        __hip_bfloat16* PB = (__hip_bfloat16*)smem;            // phase 3: 48xKST
        __hip_bfloat16* WB = (__hip_bfloat16*)(smem + 9280);   // phase 3: 32xKST
        float* meanL = smem + 12992;
        float* maxL  = smem + 16192;

        int blk = blockIdx.x;
        int qh = blk & 3;              // 16-row quarter of self side
        int sdb = blk >> 2;
        int b = sdb & 31, sd = sdb >> 5;
        int dir = sd & 1, side = sd >> 1;
        const float* selfb = side ? conh : conp;
        const float* oppb  = side ? conp : conh;

        if (t < 16) nrmA[t] = 0.f;
        if (t < 64) nrmB[t] = 0.f;
        __syncthreads();

        // ---- phase 1: stage 16 self rows (AT) + 64 opp rows (BT); atomic norms (round-1)
        for (int e = t; e < 16 * 28; e += 512) {
            int sl = e / 28, ck = e % 28, k = ck * 8;
            __align__(16) __hip_bfloat16 r8[8];
            if (k < HH) {
                const float* xp = selfb + (b * SS + qh * 16 + sl) * (2 * HH) + dir * HH + k;
                float xv[8];
                *(float4*)&xv[0] = *(const float4*)xp; *(float4*)&xv[4] = *(const float4*)(xp + 4);
                float ss = 0.f;
#pragma unroll
                for (int i = 0; i < 8; ++i) { r8[i] = __float2bfloat16(xv[i]); ss = fmaf(xv[i], xv[i], ss); }
                atomicAdd(&nrmA[sl], ss);
            } else {
#pragma unroll
                for (int i = 0; i < 8; ++i) r8[i] = __float2bfloat16(0.f);
            }
            *(bf16x8*)&AT[sl * KST + k] = *(bf16x8*)r8;
        }
        for (int e = t; e < 64 * 28; e += 512) {
            int rw = e / 28, ck = e % 28, k = ck * 8;
            __align__(16) __hip_bfloat16 r8[8];
            if (k < HH) {
                const float* xp = oppb + (b * SS + rw) * (2 * HH) + dir * HH + k;
                float xv[8];
                *(float4*)&xv[0] = *(const float4*)xp; *(float4*)&xv[4] = *(const float4*)(xp + 4);
                float ss = 0.f;
#pragma unroll
                for (int i = 0; i < 8; ++i) { r8[i] = __float2bfloat16(xv[i]); ss = fmaf(xv[i], xv[i], ss); }
                atomicAdd(&nrmB[rw], ss);
            } else {
#pragma unroll
                for (int i = 0; i < 8; ++i) r8[i] = __float2bfloat16(0.f);
            }
            *(bf16x8*)&BT[rw * KST + k] = *(bf16x8*)r8;
        }
        __syncthreads();

        int wv_ = __builtin_amdgcn_readfirstlane(t >> 6);
        int lane = t & 63;
        int q = lane >> 4, c = lane & 15;

        // ---- S = cos(A,B): 16x64 = 4 tiles, waves 0-3
        if (wv_ < 4) {
            int ct = wv_;
            f32x4 acc = (f32x4){0.f, 0.f, 0.f, 0.f};
            for (int ks = 0; ks < 7; ++ks) {
                int kb = ks * 32 + q * 8;
                bf16x8 af  = *(const bf16x8*)&AT[c * KST + kb];
                bf16x8 bf_ = *(const bf16x8*)&BT[(ct * 16 + c) * KST + kb];
                acc = __builtin_amdgcn_mfma_f32_16x16x32_bf16(af, bf_, acc, 0, 0, 0);
            }
            int col = ct * 16 + c;
            float no = sqrtf(nrmB[col]);
#pragma unroll
            for (int r = 0; r < 4; ++r) {
                int row = q * 4 + r;
                float ns = sqrtf(nrmA[row]);
                S_L[row * SST + col] = acc[r] / fmaxf(ns * no, EPS);
            }
        }
        __syncthreads();

        if (t < 16) {
            float sm = 0.f;
            for (int k = 0; k < 64; ++k) sm += S_L[t * SST + k];
            dsum[t] = fmaxf(sm, EPS);
        }
        __syncthreads();

        // ---- phase 2: attvec -> meanL / maxL (f32, in LDS)
        for (int e = t; e < 16 * 25; e += 512) {
            int s = e / 25, hc = e % 25, h0 = hc * 8;
            float dsv = dsum[s];
            float ms[8], mx[8];
#pragma unroll
            for (int i = 0; i < 8; ++i) { ms[i] = 0.f; mx[i] = -INFINITY; }
            for (int k = 0; k < 64; ++k) {
                float a = S_L[s * SST + k];
                bf16x8 ov = *(const bf16x8*)&BT[k * KST + h0];
#pragma unroll
                for (int i = 0; i < 8; ++i) {
                    float tt = a * bf2f(ov[i]);
                    ms[i] += tt;
                    mx[i] = fmaxf(mx[i], tt);
                }
            }
#pragma unroll
            for (int i = 0; i < 8; ++i) ms[i] /= dsv;
            *(float4*)&meanL[s * MHS + h0]     = *(float4*)&ms[0];
            *(float4*)&meanL[s * MHS + h0 + 4] = *(float4*)&ms[4];
            *(float4*)&maxL[s * MHS + h0]      = *(float4*)&mx[0];
            *(float4*)&maxL[s * MHS + h0 + 4]  = *(float4*)&mx[4];
        }
        __syncthreads();   // PB/WB overlays about to overwrite AT/BT/S_L

        // ---- phase 3: matches m=0 (full), m=1 (att_mean), m=2 (att_max)
        int fidx = dir ? 0 : (SS - 1);
        const float* fvr = oppb + (b * SS + fidx) * (2 * HH) + dir * HH;
        for (int m = 0; m < 3; ++m) {
            const float* wsrc = (m == 0) ? (dir ? w2 : w1)
                              : (m == 1) ? (dir ? w6 : w5)
                                         : (dir ? w8 : w7);
            // stage products [x^2 ; x*y ; y^2] (x^2 persists from m=0)
            for (int e = t; e < 16 * 28; e += 512) {
                int sl = e / 28, ck = e % 28, k = ck * 8;
                __align__(16) __hip_bfloat16 r0[8], r1[8], r2[8];
                if (k < HH) {
                    const float* xp = selfb + (b * SS + qh * 16 + sl) * (2 * HH) + dir * HH + k;
                    float xv[8], yv[8];
                    *(float4*)&xv[0] = *(const float4*)xp; *(float4*)&xv[4] = *(const float4*)(xp + 4);
                    if (m == 0) {
                        *(float4*)&yv[0] = *(const float4*)(fvr + k);
                        *(float4*)&yv[4] = *(const float4*)(fvr + k + 4);
                    } else {
                        const float* yL = (m == 1 ? meanL : maxL) + sl * MHS + k;
                        *(float4*)&yv[0] = *(const float4*)yL;
                        *(float4*)&yv[4] = *(const float4*)(yL + 4);
                    }
#pragma unroll
                    for (int i = 0; i < 8; ++i) {
                        if (m == 0) r0[i] = __float2bfloat16(xv[i] * xv[i]);
                        r1[i] = __float2bfloat16(xv[i] * yv[i]);
                        r2[i] = __float2bfloat16(yv[i] * yv[i]);
                    }
                } else {
#pragma unroll
                    for (int i = 0; i < 8; ++i) {
                        r0[i] = __float2bfloat16(0.f); r1[i] = __float2bfloat16(0.f); r2[i] = __float2bfloat16(0.f);
                    }
                }
                if (m == 0) *(bf16x8*)&PB[(0 * 16 + sl) * KST + k] = *(bf16x8*)r0;
                *(bf16x8*)&PB[(1 * 16 + sl) * KST + k] = *(bf16x8*)r1;
                *(bf16x8*)&PB[(2 * 16 + sl) * KST + k] = *(bf16x8*)r2;
            }
            // stage w^2 (rows >= 20 zero)
            for (int e = t; e < 32 * 28; e += 512) {
                int l_ = e / 28, ck = e % 28, k = ck * 8;
                __align__(16) __hip_bfloat16 wr[8];
                if (l_ < LL && k < HH) {
                    const float* wp = wsrc + l_ * HH + k;
                    float wv[8];
                    *(float4*)&wv[0] = *(const float4*)wp; *(float4*)&wv[4] = *(const float4*)(wp + 4);
#pragma unroll
                    for (int i = 0; i < 8; ++i) wr[i] = __float2bfloat16(wv[i] * wv[i]);
                } else {
#pragma unroll
                    for (int i = 0; i < 8; ++i) wr[i] = __float2bfloat16(0.f);
                }
                *(bf16x8*)&WB[l_ * KST + k] = *(bf16x8*)wr;
            }
            __syncthreads();

            if (wv_ < 2) {
                int ntile = wv_;
                f32x4 accA = (f32x4){0.f, 0.f, 0.f, 0.f};
                f32x4 accD = (f32x4){0.f, 0.f, 0.f, 0.f};
                f32x4 accB = (f32x4){0.f, 0.f, 0.f, 0.f};
                for (int ks = 0; ks < 7; ++ks) {
                    int kb = ks * 32 + q * 8;
                    bf16x8 bfw = *(const bf16x8*)&WB[(ntile * 16 + c) * KST + kb];
                    bf16x8 a0 = *(const bf16x8*)&PB[(0 * 16 + c) * KST + kb];
                    bf16x8 a1 = *(const bf16x8*)&PB[(1 * 16 + c) * KST + kb];
                    bf16x8 a2 = *(const bf16x8*)&PB[(2 * 16 + c) * KST + kb];
                    accA = __builtin_amdgcn_mfma_f32_16x16x32_bf16(a0, bfw, accA, 0, 0, 0);
                    accD = __builtin_amdgcn_mfma_f32_16x16x32_bf16(a1, bfw, accD, 0, 0, 0);
                    accB = __builtin_amdgcn_mfma_f32_16x16x32_bf16(a2, bfw, accB, 0, 0, 0);
                }
                int l_ = ntile * 16 + c;
                if (l_ < LL) {
                    int chunk = (m == 0) ? 0 : (m == 1) ? 40 : 60;
#pragma unroll
                    for (int r = 0; r < 4; ++r) {
                        int s = qh * 16 + q * 4 + r;
                        float cosv = accD[r] / fmaxf(sqrtf(accA[r] * accB[r]), EPS);
                        out[side * (BB * SS * 160) + (b * SS + s) * 160 + dir * 80 + chunk + l_] = cosv;
                    }
                }
            }
            if (m < 2) __syncthreads();
        }
    } else {
        // ================================ type C: pairwise bf16 MFMA (VERBATIM round-1)
        __hip_bfloat16* AT = (__hip_bfloat16*)smem;            // 64*KST bf16
        __hip_bfloat16* BT = (__hip_bfloat16*)(smem + 7424);   // 64*KST bf16
        float* cmL = smem + 14848;                             // 256 fl
        float* nA  = smem + 15104;                             // 64
        float* nB  = smem + 15168;                             // 64
        int blk = blockIdx.x - 512;
        int l = blk % LL; int db = blk / LL; int b = db & 31; int dir = db >> 5;

        const float* wrow = (dir ? w4 : w3) + l * HH;
        const float* Ag = conp + dir * HH;
        const float* Bg = conh + dir * HH;

        if (t < 64) { nA[t] = 0.f; nB[t] = 0.f; }
        __syncthreads();

        for (int e = t; e < 64 * 28; e += 512) {
            int m = e / 28, ck = e - m * 28;
            int k = ck * 8;
            __align__(16) __hip_bfloat16 at8[8];
            __align__(16) __hip_bfloat16 bt8[8];
            if (k < HH) {
                const float* ap = Ag + (b * SS + m) * (2 * HH) + k;
                const float* bp = Bg + (b * SS + m) * (2 * HH) + k;
                const float* wp = wrow + k;
                float av[8], bv[8], wvv[8];
                *(float4*)&av[0]  = *(const float4*)ap; *(float4*)&av[4]  = *(const float4*)(ap + 4);
                *(float4*)&bv[0]  = *(const float4*)bp; *(float4*)&bv[4]  = *(const float4*)(bp + 4);
                *(float4*)&wvv[0] = *(const float4*)wp; *(float4*)&wvv[4] = *(const float4*)(wp + 4);
                float ssa = 0.f, ssb = 0.f;
#pragma unroll
                for (int i = 0; i < 8; ++i) {
                    float aw = av[i] * wvv[i];
                    float bw = bv[i] * wvv[i];
                    at8[i] = __float2bfloat16(aw);
                    bt8[i] = __float2bfloat16(bw);
                    ssa = fmaf(aw, aw, ssa);
                    ssb = fmaf(bw, bw, ssb);
                }
                atomicAdd(&nA[m], ssa);
                atomicAdd(&nB[m], ssb);
            } else {
#pragma unroll
                for (int ii = 0; ii < 8; ++ii) { at8[ii] = __float2bfloat16(0.f); bt8[ii] = __float2bfloat16(0.f); }
            }
            *(bf16x8*)&AT[m * KST + k] = *(bf16x8*)at8;
            *(bf16x8*)&BT[m * KST + k] = *(bf16x8*)bt8;
        }
        __syncthreads();

        int wv_ = __builtin_amdgcn_readfirstlane(t >> 6);
        int lane = t & 63;
        int q = lane >> 4, c = lane & 15;

        if (wv_ < 4) {
            int m0 = wv_ * 16;
            f32x4 acc[4];
#pragma unroll
            for (int ct = 0; ct < 4; ++ct) acc[ct] = (f32x4){0.f, 0.f, 0.f, 0.f};

            for (int ks = 0; ks < 7; ++ks) {
                int kb = ks * 32 + q * 8;
                bf16x8 af = *(const bf16x8*)&AT[(m0 + c) * KST + kb];
#pragma unroll
                for (int ct = 0; ct < 4; ++ct) {
                    bf16x8 bf_ = *(const bf16x8*)&BT[(ct * 16 + c) * KST + kb];
                    acc[ct] = __builtin_amdgcn_mfma_f32_16x16x32_bf16(af, bf_, acc[ct], 0, 0, 0);
                }
            }

            float na[4], nb[4];
#pragma unroll
            for (int r = 0; r < 4; ++r) na[r] = sqrtf(nA[m0 + q * 4 + r]);
#pragma unroll
            for (int ct = 0; ct < 4; ++ct) nb[ct] = sqrtf(nB[ct * 16 + c]);

            float rowm[4] = {-INFINITY, -INFINITY, -INFINITY, -INFINITY};
            float colm[4] = {-INFINITY, -INFINITY, -INFINITY, -INFINITY};
#pragma unroll
            for (int ct = 0; ct < 4; ++ct) {
#pragma unroll
                for (int r = 0; r < 4; ++r) {
                    float cv = acc[ct][r] / fmaxf(na[r] * nb[ct], EPS);
                    rowm[r] = fmaxf(rowm[r], cv);
                    colm[ct] = fmaxf(colm[ct], cv);
                }
            }

#pragma unroll
            for (int r = 0; r < 4; ++r) {
                float v = rowm[r];
                v = fmaxf(v, __shfl_xor(v, 1, 64));
                v = fmaxf(v, __shfl_xor(v, 2, 64));
                v = fmaxf(v, __shfl_xor(v, 4, 64));
                v = fmaxf(v, __shfl_xor(v, 8, 64));
                rowm[r] = v;
            }
            if (c == 0) {
#pragma unroll
                for (int r = 0; r < 4; ++r) {
                    int i = m0 + q * 4 + r;
                    out[(b * SS + i) * 160 + dir * 80 + 20 + l] = rowm[r];
                }
            }

#pragma unroll
            for (int ct = 0; ct < 4; ++ct) {
                float v = colm[ct];
                v = fmaxf(v, __shfl_xor(v, 16, 64));
                v = fmaxf(v, __shfl_xor(v, 32, 64));
                colm[ct] = v;
            }
            if (q == 0) {
#pragma unroll
                for (int ct = 0; ct < 4; ++ct) cmL[wv_ * 64 + ct * 16 + c] = colm[ct];
            }
        }
        __syncthreads();
        if (t < 64) {
            float m = fmaxf(fmaxf(cmL[t], cmL[64 + t]), fmaxf(cmL[128 + t], cmL[192 + t]));
            out[BB * SS * 160 + (b * SS + t) * 160 + dir * 80 + 20 + l] = m;
        }
    }
}

extern "C" void kernel_launch(void* const* d_in, const int* in_sizes, int n_in,
                              void* d_out, int out_size, void* d_ws, size_t ws_size,
                              hipStream_t stream) {
    const float* conp = (const float*)d_in[0];
    const float* conh = (const float*)d_in[1];
    const float* w1 = (const float*)d_in[2];
    const float* w2 = (const float*)d_in[3];
    const float* w3 = (const float*)d_in[4];
    const float* w4 = (const float*)d_in[5];
    const float* w5 = (const float*)d_in[6];
    const float* w6 = (const float*)d_in[7];
    const float* w7 = (const float*)d_in[8];
    const float* w8 = (const float*)d_in[9];
    float* out = (float*)d_out;
    (void)d_ws; (void)ws_size;

    fused_all_kernel<<<1792, 512, 0, stream>>>(conp, conh,
                                               w1, w2, w3, w4, w5, w6, w7, w8, out);
}